// Round 8
// baseline (1353.256 us; speedup 1.0000x reference)
//
#include <hip/hip_runtime.h>
#include <hip/hip_bf16.h>

#define NN 100000
#define EE 400000
#define GG 1024

typedef _Float16 half_t;
typedef _Float16 f16x8 __attribute__((ext_vector_type(8)));
typedef float f32x4 __attribute__((ext_vector_type(4)));
typedef float f32x2 __attribute__((ext_vector_type(2)));

#define GLOAD_LDS(g, l) \
    __builtin_amdgcn_global_load_lds((const __attribute__((address_space(1))) void*)(g), \
                                     (__attribute__((address_space(3))) void*)(l), 16, 0, 0)

// ---------------- merged CSR build (both encoders as one 2N-node graph) ----------------

__global__ void k_count2(const int* __restrict__ ei1, const int* __restrict__ ei2,
                         int* __restrict__ deg) {
    int e = blockIdx.x * 256 + threadIdx.x;
    if (e >= 2 * EE) return;
    int enc = e >= EE;
    const int* ei = enc ? ei2 : ei1;
    int le = e - enc * EE;
    atomicAdd(&deg[enc * NN + ei[EE + le]], 1);
}

__global__ void k_scan_bsum(const int* __restrict__ deg, int* __restrict__ bsum, int total) {
    __shared__ int lds[256];
    int t = threadIdx.x;
    int base = blockIdx.x * 1024 + t * 4;
    int s = 0;
#pragma unroll
    for (int i = 0; i < 4; ++i) { int idx = base + i; s += (idx < total) ? deg[idx] : 0; }
    lds[t] = s;
    __syncthreads();
    for (int off = 128; off > 0; off >>= 1) {
        if (t < off) lds[t] += lds[t + off];
        __syncthreads();
    }
    if (t == 0) bsum[blockIdx.x] = lds[0];
}

__global__ void k_scan_write(const int* __restrict__ deg, const int* __restrict__ bsum,
                             int* __restrict__ rowptr, float* __restrict__ dinv,
                             int total, int totedge) {
    __shared__ int lds[256];
    __shared__ int blockoff;
    int t = threadIdx.x;
    if (t == 0) {
        int off = 0;
        for (int b = 0; b < (int)blockIdx.x; ++b) off += bsum[b];
        blockoff = off;
    }
    int base = blockIdx.x * 1024 + t * 4;
    int v[4]; int ts = 0;
#pragma unroll
    for (int i = 0; i < 4; ++i) { int idx = base + i; v[i] = (idx < total) ? deg[idx] : 0; ts += v[i]; }
    lds[t] = ts;
    __syncthreads();
    for (int off = 1; off < 256; off <<= 1) {
        int x = (t >= off) ? lds[t - off] : 0;
        __syncthreads();
        lds[t] += x;
        __syncthreads();
    }
    int excl = lds[t] - ts + blockoff;
#pragma unroll
    for (int i = 0; i < 4; ++i) {
        int idx = base + i;
        if (idx < total) {
            rowptr[idx] = excl;
            dinv[idx] = rsqrtf((float)v[i] + 1.0f);
        }
        excl += v[i];
    }
    if (blockIdx.x == 0 && t == 0) rowptr[total] = totedge;
}

__global__ void k_fill2(const int* __restrict__ ei1, const int* __restrict__ ei2,
                        const int* __restrict__ rowptr, int* __restrict__ cnt,
                        int* __restrict__ colv) {
    int e = blockIdx.x * 256 + threadIdx.x;
    if (e >= 2 * EE) return;
    int enc = e >= EE;
    const int* ei = enc ? ei2 : ei1;
    int le = e - enc * EE;
    int s = ei[le], d = ei[EE + le];
    int gd = enc * NN + d;
    int pos = rowptr[gd] + atomicAdd(&cnt[gd], 1);
    colv[pos] = s;   // local source id
}

__global__ void k_starts2(const int* __restrict__ b1, const int* __restrict__ b2,
                          int* __restrict__ gstart) {
    int i = blockIdx.x * 256 + threadIdx.x;
    if (i >= 2 * NN) return;
    int enc = i >= NN;
    int il = i - enc * NN;
    const int* bat = enc ? b2 : b1;
    int* gs = gstart + enc * (GG + 1);
    int b = bat[il];
    if (il == 0) {
        for (int g = 0; g <= b; ++g) gs[g] = 0;
    } else {
        int pb = bat[il - 1];
        for (int g = pb + 1; g <= b; ++g) gs[g] = il;
    }
    if (il == NN - 1) {
        for (int g = b + 1; g <= GG; ++g) gs[g] = NN;
    }
}

// ---------------- aggregation device bodies (+ f16 hi/lo split output) ----------------

// F=90: rows 360B (float2-aligned). 45 lanes x float2. KPAD=128.
__device__ __forceinline__ void dev_agg90(int blk, const float* __restrict__ x,
                                          const float* __restrict__ dinv,
                                          const int* __restrict__ rowptr,
                                          const int* __restrict__ col,
                                          half_t* __restrict__ out) {
    int wave = threadIdx.x >> 6;
    int lane = threadIdx.x & 63;
    int n = blk * 4 + wave;
    if (n >= NN) return;
    bool al = lane < 45;
    float dn = dinv[n];
    f32x2 acc = {0.f, 0.f};
    if (al) acc = dn * ((const f32x2*)(x + (size_t)n * 90))[lane];
    int j0 = rowptr[n], j1 = rowptr[n + 1];
    int j = j0;
    for (; j + 4 <= j1; j += 4) {
        int s0 = col[j], s1 = col[j + 1], s2 = col[j + 2], s3 = col[j + 3];
        float d0 = dinv[s0], d1 = dinv[s1], d2 = dinv[s2], d3 = dinv[s3];
        if (al) {
            f32x2 v0 = ((const f32x2*)(x + (size_t)s0 * 90))[lane];
            f32x2 v1 = ((const f32x2*)(x + (size_t)s1 * 90))[lane];
            f32x2 v2 = ((const f32x2*)(x + (size_t)s2 * 90))[lane];
            f32x2 v3 = ((const f32x2*)(x + (size_t)s3 * 90))[lane];
            acc += d0 * v0; acc += d1 * v1; acc += d2 * v2; acc += d3 * v3;
        }
    }
    for (; j < j1; ++j) {
        int s = col[j];
        float ds = dinv[s];
        if (al) acc += ds * ((const f32x2*)(x + (size_t)s * 90))[lane];
    }
    float v0 = al ? dn * acc[0] : 0.f;
    float v1 = al ? dn * acc[1] : 0.f;
    half_t h0 = (half_t)v0, l0 = (half_t)(v0 - (float)h0);
    half_t h1 = (half_t)v1, l1 = (half_t)(v1 - (float)h1);
    half_t* o = out + (size_t)n * 256;
    o[2 * lane] = h0;
    o[2 * lane + 1] = h1;
    o[128 + 2 * lane] = l0;
    o[128 + 2 * lane + 1] = l1;
}

// F = KPAD = 64*VW, one float-vector per lane, 4-way neighbor unroll.
template <int VW>
__device__ __forceinline__ void dev_aggv(int blk, const float* __restrict__ x,
                                         const float* __restrict__ dinv,
                                         const int* __restrict__ rowptr,
                                         const int* __restrict__ col,
                                         half_t* __restrict__ out) {
    constexpr int F = 64 * VW;
    typedef float fvec __attribute__((ext_vector_type(VW)));
    int wave = threadIdx.x >> 6;
    int lane = threadIdx.x & 63;
    int n = blk * 4 + wave;
    if (n >= NN) return;
    float dn = dinv[n];
    fvec acc = dn * ((const fvec*)(x + (size_t)n * F))[lane];
    int j0 = rowptr[n], j1 = rowptr[n + 1];
    int j = j0;
    for (; j + 4 <= j1; j += 4) {
        int s0 = col[j], s1 = col[j + 1], s2 = col[j + 2], s3 = col[j + 3];
        float d0 = dinv[s0], d1 = dinv[s1], d2 = dinv[s2], d3 = dinv[s3];
        fvec v0 = ((const fvec*)(x + (size_t)s0 * F))[lane];
        fvec v1 = ((const fvec*)(x + (size_t)s1 * F))[lane];
        fvec v2 = ((const fvec*)(x + (size_t)s2 * F))[lane];
        fvec v3 = ((const fvec*)(x + (size_t)s3 * F))[lane];
        acc += d0 * v0; acc += d1 * v1; acc += d2 * v2; acc += d3 * v3;
    }
    for (; j < j1; ++j) {
        int s = col[j];
        acc += dinv[s] * ((const fvec*)(x + (size_t)s * F))[lane];
    }
    half_t* o = out + (size_t)n * (2 * F);
    half_t hv[VW], lv[VW];
#pragma unroll
    for (int i = 0; i < VW; ++i) {
        float v = dn * acc[i];
        hv[i] = (half_t)v;
        lv[i] = (half_t)(v - (float)hv[i]);
    }
#pragma unroll
    for (int i = 0; i < VW; ++i) o[lane * VW + i] = hv[i];
#pragma unroll
    for (int i = 0; i < VW; ++i) o[F + lane * VW + i] = lv[i];
}

// ---------------- MFMA GEMM device body ----------------
// C[M][Nc] = relu(A@W + bias) via split-precision augmented K (see r1 notes).
// 128x128 tile, 4 waves (2x2), 16x16x32 f16 MFMA, BK=64, XOR-swizzled LDS.

template <bool RELU>
__device__ __forceinline__ void dev_gemm(int bx, int by,
    const half_t* __restrict__ Ap, const half_t* __restrict__ Bt,
    const float* __restrict__ bias, float* __restrict__ C,
    int M, int Kpad, int Nc) {
    __shared__ half_t As[128 * 64];
    __shared__ half_t Bs[128 * 64];
    const int tid = threadIdx.x;
    const int wave = tid >> 6, lane = tid & 63;
    const int wm = wave >> 1, wn = wave & 1;
    const int bm = bx * 128, bn = by * 128;
    const int KA = 2 * Kpad, KB = 3 * Kpad;
    const int nkt = KB >> 6;
    const int aTiles = KA >> 6;

    f32x4 acc[4][4] = {};

    const int srow = tid >> 3;
    const int ch = tid & 7;

    for (int kt = 0; kt < nkt; ++kt) {
        int ka0 = ((kt < aTiles) ? kt : (kt - aTiles)) << 6;
        int kb0 = kt << 6;
        __syncthreads();
#pragma unroll
        for (int i = 0; i < 4; ++i) {
            int rl = i * 32 + srow;
            int sch = ch ^ (rl & 7);
            int gr = bm + rl; if (gr >= M) gr = M - 1;
            const half_t* ga = Ap + (size_t)gr * KA + ka0 + sch * 8;
            GLOAD_LDS(ga, (char*)As + i * 4096 + wave * 1024);
        }
#pragma unroll
        for (int i = 0; i < 4; ++i) {
            int rl = i * 32 + srow;
            int sch = ch ^ (rl & 7);
            const half_t* gb = Bt + (size_t)(bn + rl) * KB + kb0 + sch * 8;
            GLOAD_LDS(gb, (char*)Bs + i * 4096 + wave * 1024);
        }
        __syncthreads();
#pragma unroll
        for (int s = 0; s < 2; ++s) {
            f16x8 af[4], bf[4];
#pragma unroll
            for (int i = 0; i < 4; ++i) {
                int row = wm * 64 + i * 16 + (lane & 15);
                int c = s * 4 + (lane >> 4);
                af[i] = *(const f16x8*)&As[row * 64 + ((c ^ (row & 7)) << 3)];
            }
#pragma unroll
            for (int j = 0; j < 4; ++j) {
                int row = wn * 64 + j * 16 + (lane & 15);
                int c = s * 4 + (lane >> 4);
                bf[j] = *(const f16x8*)&Bs[row * 64 + ((c ^ (row & 7)) << 3)];
            }
#pragma unroll
            for (int i = 0; i < 4; ++i)
#pragma unroll
                for (int j = 0; j < 4; ++j)
                    acc[i][j] = __builtin_amdgcn_mfma_f32_16x16x32_f16(af[i], bf[j], acc[i][j], 0, 0, 0);
        }
    }

#pragma unroll
    for (int i = 0; i < 4; ++i) {
#pragma unroll
        for (int j = 0; j < 4; ++j) {
            int cc = bn + wn * 64 + j * 16 + (lane & 15);
            float bv = bias[cc];
            int r0 = bm + wm * 64 + i * 16 + (lane >> 4) * 4;
#pragma unroll
            for (int q = 0; q < 4; ++q) {
                int gr = r0 + q;
                if (gr < M) {
                    float v = acc[i][j][q] + bv;
                    if (RELU) v = fmaxf(v, 0.f);
                    C[(size_t)gr * Nc + cc] = v;
                }
            }
        }
    }
}

// ---------------- standalone kernels ----------------

__global__ void k_agg90(const float* __restrict__ x, const float* __restrict__ dinv,
                        const int* __restrict__ rowptr, const int* __restrict__ col,
                        half_t* __restrict__ out) {
    dev_agg90(blockIdx.x, x, dinv, rowptr, col, out);
}

template <int VW>
__global__ void k_agg_splitv(const float* __restrict__ x, const float* __restrict__ dinv,
                             const int* __restrict__ rowptr, const int* __restrict__ col,
                             half_t* __restrict__ out) {
    dev_aggv<VW>(blockIdx.x, x, dinv, rowptr, col, out);
}

template <bool RELU>
__global__ __launch_bounds__(256, 2)
void k_mgemm(const half_t* __restrict__ Ap, const half_t* __restrict__ Bt,
             const float* __restrict__ bias, float* __restrict__ C,
             int M, int Kpad, int Nc) {
    dev_gemm<RELU>(blockIdx.x, blockIdx.y, Ap, Bt, bias, C, M, Kpad, Nc);
}

// ---------------- fused heterogeneous dispatch: gemm blocks striped among agg blocks ----
// blockIdx = q*stride + r. gemm block iff (r==0 && q<gemmBlocks), id q -> (q%mt, q/mt).
// otherwise agg block, id = blockIdx - min(q + (r>0), gemmBlocks).

template <int AGGV>
__global__ __launch_bounds__(256, 2)
void k_fused(int stride, int gemmBlocks, int mt,
             const half_t* __restrict__ Ap, const half_t* __restrict__ Bt,
             const float* __restrict__ bias, float* __restrict__ C,
             int M, int Kpad, int Nc,
             const float* __restrict__ xa, const float* __restrict__ dva,
             const int* __restrict__ rpa, const int* __restrict__ cola,
             half_t* __restrict__ outa) {
    int q = blockIdx.x / stride, r = blockIdx.x - q * stride;
    if (r == 0 && q < gemmBlocks) {
        dev_gemm<true>(q % mt, q / mt, Ap, Bt, bias, C, M, Kpad, Nc);
    } else {
        int before = (q < gemmBlocks) ? (q + (r > 0 ? 1 : 0)) : gemmBlocks;
        int aggIdx = blockIdx.x - before;
        if constexpr (AGGV == 90) dev_agg90(aggIdx, xa, dva, rpa, cola, outa);
        else dev_aggv<AGGV>(aggIdx, xa, dva, rpa, cola, outa);
    }
}

// ---------------- weight prep / split ----------------

__global__ void k_wprep(const float* __restrict__ W, half_t* __restrict__ Bt,
                        int K, int Kpad, int Nc) {
    int t = blockIdx.x * 256 + threadIdx.x;
    if (t >= Nc * Kpad) return;
    int n = t / Kpad, kp = t % Kpad;
    half_t h = (half_t)0.f, l = (half_t)0.f;
    if (kp < K) {
        float w = W[(size_t)kp * Nc + n];
        h = (half_t)w;
        l = (half_t)(w - (float)h);
    }
    half_t* o = Bt + (size_t)n * 3 * Kpad;
    o[kp] = h;
    o[Kpad + kp] = h;
    o[2 * Kpad + kp] = l;
}

__global__ void k_split(const float* __restrict__ in, half_t* __restrict__ out, int K) {
    int t = blockIdx.x * 256 + threadIdx.x;
    int row = t / K, k = t % K;
    float v = in[t];
    half_t h = (half_t)v;
    half_t l = (half_t)(v - (float)h);
    half_t* o = out + (size_t)row * 2 * K;
    o[k] = h;
    o[K + k] = l;
}

// ---------------- pooling ----------------

__global__ void k_pool(const float* __restrict__ act, const int* __restrict__ gstart,
                       float* __restrict__ h) {
    int g = blockIdx.x;
    int f = threadIdx.x;
    int s = gstart[g], e = gstart[g + 1];
    float mx = 0.f, sm = 0.f;
    for (int i = s; i < e; ++i) {
        float v = act[(size_t)i * 256 + f];
        mx = fmaxf(mx, v);
        sm += v;
    }
    float cnt = (float)(e - s);
    h[(size_t)g * 512 + f] = mx;
    h[(size_t)g * 512 + 256 + f] = (cnt > 0.f) ? sm / cnt : 0.f;
}

__global__ void k_pool2(const float* __restrict__ a1, const float* __restrict__ a2,
                        const int* __restrict__ gstart, float* __restrict__ h) {
    int enc = blockIdx.x >> 10;
    int g = blockIdx.x & 1023;
    const float* act = enc ? a2 : a1;
    const int* gs = gstart + enc * (GG + 1);
    int f = threadIdx.x;
    int s = gs[g], e = gs[g + 1];
    float mx = 0.f, sm = 0.f;
    for (int i = s; i < e; ++i) {
        float v = act[(size_t)i * 256 + f];
        mx = fmaxf(mx, v);
        sm += v;
    }
    float cnt = (float)(e - s);
    float* o = h + (size_t)enc * GG * 512;
    o[(size_t)g * 512 + f] = mx;
    o[(size_t)g * 512 + 256 + f] = (cnt > 0.f) ? sm / cnt : 0.f;
}

// ---------------- head ----------------

__global__ void k_headin_split(const float* __restrict__ h, half_t* __restrict__ xh) {
    int t = blockIdx.x * blockDim.x + threadIdx.x;
    if (t >= GG * 1024) return;
    int g = t >> 10, j = t & 1023;
    const float* h1 = h + (size_t)g * 512;
    const float* h2 = h + (size_t)(GG + g) * 512;
    float v = (j < 512) ? (h1[j] - h2[j]) : (h2[j - 512] - h1[j - 512]);
    half_t hi = (half_t)v;
    half_t lo = (half_t)(v - (float)hi);
    half_t* o = xh + (size_t)g * 2048;
    o[j] = hi;
    o[1024 + j] = lo;
}

__global__ void k_fc3(const float* __restrict__ A, const float* __restrict__ W,
                      const float* __restrict__ b, float* __restrict__ out) {
    int g = blockIdx.x * 4 + (threadIdx.x >> 6);
    int lane = threadIdx.x & 63;
    const float* a = A + (size_t)g * 256;
    float p = a[lane] * W[lane] + a[lane + 64] * W[lane + 64]
            + a[lane + 128] * W[lane + 128] + a[lane + 192] * W[lane + 192];
    for (int off = 32; off > 0; off >>= 1) p += __shfl_down(p, off);
    if (lane == 0) out[g] = tanhf(p + b[0]);
}

// ---------------- launch ----------------

extern "C" void kernel_launch(void* const* d_in, const int* in_sizes, int n_in,
                              void* d_out, int out_size, void* d_ws, size_t ws_size,
                              hipStream_t stream) {
    const float* x1  = (const float*)d_in[0];
    const int*   ei1 = (const int*)d_in[1];
    const int*   ba1 = (const int*)d_in[2];
    const float* x2  = (const float*)d_in[3];
    const int*   ei2 = (const int*)d_in[4];
    const int*   ba2 = (const int*)d_in[5];
    const float* W1 = (const float*)d_in[6];
    const float* b1 = (const float*)d_in[7];
    const float* W2 = (const float*)d_in[8];
    const float* b2 = (const float*)d_in[9];
    const float* W3 = (const float*)d_in[10];
    const float* b3 = (const float*)d_in[11];
    const float* W4 = (const float*)d_in[12];
    const float* b4 = (const float*)d_in[13];
    const float* fc1W = (const float*)d_in[14];
    const float* fc1b = (const float*)d_in[15];
    const float* fc2W = (const float*)d_in[16];
    const float* fc2b = (const float*)d_in[17];
    const float* fc3W = (const float*)d_in[18];
    const float* fc3b = (const float*)d_in[19];
    float* out = (float*)d_out;

    const bool pipe = ws_size >= (size_t)435000000ull;

    char* ws = (char*)d_ws;
    size_t off = 0;
    auto alloc = [&](size_t bytes) -> void* {
        void* p = (void*)(ws + off);
        off += (bytes + 255) & ~(size_t)255;
        return p;
    };
    int*    dc     = (int*)alloc((size_t)4 * NN * sizeof(int));
    int*    rowptr = (int*)alloc((size_t)(2 * NN + 1) * sizeof(int));
    int*    colv   = (int*)alloc((size_t)2 * EE * sizeof(int));
    int*    bsum   = (int*)alloc(256 * sizeof(int));
    int*    gstart = (int*)alloc((size_t)2 * (GG + 1) * sizeof(int));
    float*  dinv   = (float*)alloc((size_t)2 * NN * sizeof(float));
    half_t* Ap1    = (half_t*)alloc((size_t)NN * 512 * sizeof(half_t));
    float*  act1   = (float*)alloc((size_t)NN * 256 * sizeof(float));
    half_t* Ap2    = pipe ? (half_t*)alloc((size_t)NN * 512 * sizeof(half_t)) : Ap1;
    float*  act2   = pipe ? (float*)alloc((size_t)NN * 256 * sizeof(float)) : act1;
    half_t* Bt1    = (half_t*)alloc((size_t)128 * 384 * sizeof(half_t));
    half_t* Bt2    = (half_t*)alloc((size_t)256 * 384 * sizeof(half_t));
    half_t* Bt3    = (half_t*)alloc((size_t)256 * 768 * sizeof(half_t));
    half_t* Bt4    = (half_t*)alloc((size_t)256 * 768 * sizeof(half_t));
    half_t* Btf1   = (half_t*)alloc((size_t)512 * 3072 * sizeof(half_t));
    half_t* Btf2   = (half_t*)alloc((size_t)256 * 1536 * sizeof(half_t));
    float*  hpool  = (float*)alloc((size_t)2 * GG * 512 * sizeof(float));
    half_t* xhs    = (half_t*)alloc((size_t)GG * 2048 * sizeof(half_t));
    float*  t1     = (float*)alloc((size_t)GG * 512 * sizeof(float));
    half_t* t1s    = (half_t*)alloc((size_t)GG * 1024 * sizeof(half_t));
    float*  t2     = (float*)alloc((size_t)GG * 256 * sizeof(float));

    int* deg = dc;
    int* cnt = dc + 2 * NN;

    int nsb2 = (2 * NN + 1023) / 1024;
    int mt = (NN + 127) / 128;           // 782
    int aggB = (NN + 3) / 4;             // 25000

    // weight prep (shared across both encoders + head)
    k_wprep<<<(128 * 128 + 255) / 256, 256, 0, stream>>>(W1, Bt1, 90, 128, 128);
    k_wprep<<<(256 * 128 + 255) / 256, 256, 0, stream>>>(W2, Bt2, 128, 128, 256);
    k_wprep<<<(256 * 256 + 255) / 256, 256, 0, stream>>>(W3, Bt3, 256, 256, 256);
    k_wprep<<<(256 * 256 + 255) / 256, 256, 0, stream>>>(W4, Bt4, 256, 256, 256);
    k_wprep<<<(512 * 1024 + 255) / 256, 256, 0, stream>>>(fc1W, Btf1, 1024, 1024, 512);
    k_wprep<<<(256 * 512 + 255) / 256, 256, 0, stream>>>(fc2W, Btf2, 512, 512, 256);

    // merged CSR build (once for both encoders)
    hipMemsetAsync(dc, 0, (size_t)4 * NN * sizeof(int), stream);
    k_count2<<<(2 * EE + 255) / 256, 256, 0, stream>>>(ei1, ei2, deg);
    k_scan_bsum<<<nsb2, 256, 0, stream>>>(deg, bsum, 2 * NN);
    k_scan_write<<<nsb2, 256, 0, stream>>>(deg, bsum, rowptr, dinv, 2 * NN, 2 * EE);
    k_fill2<<<(2 * EE + 255) / 256, 256, 0, stream>>>(ei1, ei2, rowptr, cnt, colv);
    k_starts2<<<(2 * NN + 255) / 256, 256, 0, stream>>>(ba1, ba2, gstart);

    const int*   rp1 = rowptr;          const int*   rp2 = rowptr + NN;
    const float* dv1 = dinv;            const float* dv2 = dinv + NN;

    if (pipe) {
        // ping-pong: gemm(encA, Li) co-dispatched with agg(encB, Li)
        auto FUSED = [&](auto aggvTag, const half_t* Ap, const half_t* Bt, const float* bias,
                         float* C, int Kpad, int Nc,
                         const float* xa, const float* dva, const int* rpa, half_t* outa) {
            constexpr int AGGV = decltype(aggvTag)::value;
            int gB = mt * (Nc / 128);
            int total = aggB + gB;
            int stride = total / gB;
            k_fused<AGGV><<<total, 256, 0, stream>>>(stride, gB, mt, Ap, Bt, bias, C,
                                                     NN, Kpad, Nc, xa, dva, rpa, colv, outa);
        };
        using I90 = std::integral_constant<int, 90>;
        using I2  = std::integral_constant<int, 2>;
        using I4  = std::integral_constant<int, 4>;

        k_agg90<<<aggB, 256, 0, stream>>>(x1, dv1, rp1, colv, Ap1);
        FUSED(I90{}, Ap1, Bt1, b1, act1, 128, 128, x2,   dv2, rp2, Ap2);   // G(e1,L1) || A(e2,L1)
        FUSED(I2{},  Ap2, Bt1, b1, act2, 128, 128, act1, dv1, rp1, Ap1);   // G(e2,L1) || A(e1,L2)
        FUSED(I2{},  Ap1, Bt2, b2, act1, 128, 256, act2, dv2, rp2, Ap2);   // G(e1,L2) || A(e2,L2)
        FUSED(I4{},  Ap2, Bt2, b2, act2, 128, 256, act1, dv1, rp1, Ap1);   // G(e2,L2) || A(e1,L3)
        FUSED(I4{},  Ap1, Bt3, b3, act1, 256, 256, act2, dv2, rp2, Ap2);   // G(e1,L3) || A(e2,L3)
        FUSED(I4{},  Ap2, Bt3, b3, act2, 256, 256, act1, dv1, rp1, Ap1);   // G(e2,L3) || A(e1,L4)
        FUSED(I4{},  Ap1, Bt4, b4, act1, 256, 256, act2, dv2, rp2, Ap2);   // G(e1,L4) || A(e2,L4)
        k_mgemm<true><<<dim3(mt, 2), 256, 0, stream>>>(Ap2, Bt4, b4, act2, NN, 256, 256); // G(e2,L4)
        k_pool2<<<2 * GG, 256, 0, stream>>>(act1, act2, gstart, hpool);
    } else {
        // sequential fallback (round-7 proven schedule)
        for (int p = 0; p < 2; ++p) {
            const float* x  = p ? x2 : x1;
            const int*   rp = p ? rp2 : rp1;
            const float* dv = p ? dv2 : dv1;
            const int*   gs = gstart + p * (GG + 1);
            k_agg90<<<aggB, 256, 0, stream>>>(x, dv, rp, colv, Ap1);
            k_mgemm<true><<<dim3(mt, 1), 256, 0, stream>>>(Ap1, Bt1, b1, act1, NN, 128, 128);
            k_agg_splitv<2><<<aggB, 256, 0, stream>>>(act1, dv, rp, colv, Ap1);
            k_mgemm<true><<<dim3(mt, 2), 256, 0, stream>>>(Ap1, Bt2, b2, act1, NN, 128, 256);
            k_agg_splitv<4><<<aggB, 256, 0, stream>>>(act1, dv, rp, colv, Ap1);
            k_mgemm<true><<<dim3(mt, 2), 256, 0, stream>>>(Ap1, Bt3, b3, act1, NN, 256, 256);
            k_agg_splitv<4><<<aggB, 256, 0, stream>>>(act1, dv, rp, colv, Ap1);
            k_mgemm<true><<<dim3(mt, 2), 256, 0, stream>>>(Ap1, Bt4, b4, act1, NN, 256, 256);
            k_pool<<<GG, 256, 0, stream>>>(act1, gs, hpool + (size_t)p * GG * 512);
        }
    }

    // head: split-precision MFMA for fc1/fc2, wave-reduce for fc3
    k_headin_split<<<(GG * 1024 + 255) / 256, 256, 0, stream>>>(hpool, xhs);
    k_mgemm<true><<<dim3(GG / 128, 4), 256, 0, stream>>>(xhs, Btf1, fc1b, t1, GG, 1024, 512);
    k_split<<<(GG * 512 + 255) / 256, 256, 0, stream>>>(t1, t1s, 512);
    k_mgemm<true><<<dim3(GG / 128, 2), 256, 0, stream>>>(t1s, Btf2, fc2b, t2, GG, 512, 256);
    k_fc3<<<GG / 4, 256, 0, stream>>>(t2, fc3W, fc3b, out);
}